// Round 13
// baseline (279.562 us; speedup 1.0000x reference)
//
#include <hip/hip_runtime.h>

#define H    64
#define F    256
#define NSEG 256
#define SCB  2048   // scan elements per block
#define MB   64     // qkv node rows per tile
#define KC   64     // qkv K chunk
#define NSPAN_MAX 8192
#define NCHUNK 16   // edge chunks for hist/reorder (shared chunking)

typedef float          f32x4v __attribute__((ext_vector_type(4)));
typedef short          bf16x8 __attribute__((ext_vector_type(8)));
typedef unsigned short u16x4  __attribute__((ext_vector_type(4)));

// ---------------------------------------------------------------------------
// In-degree histogram: LDS-privatized, zero global atomics (R9-verified
// structure; now NCHUNK=16 chunks to match reorder).  Grid = 8 spans x 16
// chunks; LDS histogram per block; non-atomic flush to countsC[chunk]
// (each (chunk,node) cell written by exactly one block -> no init needed).
// ---------------------------------------------------------------------------
__global__ __launch_bounds__(1024) void hist_kernel(
    const int* __restrict__ ei, int* __restrict__ countsC,
    int N, int E, int nspan)
{
    __shared__ int lh[NSPAN_MAX];
    const int p  = blockIdx.x & 7;           // span class
    const int c  = blockIdx.x >> 3;          // edge chunk 0..NCHUNK-1
    const int lo = p * nspan;
    const int span = min(N - lo, nspan);
    const int t = threadIdx.x;

    for (int i = t; i < span; i += 1024) lh[i] = 0;
    __syncthreads();

    const int epc = (E + NCHUNK - 1) / NCHUNK;
    const int e0 = c * epc;
    const int e1 = min(E, e0 + epc);

    if (((E | e0) & 3) == 0) {               // 16B-aligned vector path
        const int nv = (e1 - e0) >> 2;
        for (int i = t; i < nv; i += 1024) {
            const int4 d4 = *(const int4*)(ei + E + e0 + i * 4);
            int d;
            d = min(max(d4.x, 0), N - 1) - lo; if ((unsigned)d < (unsigned)span) atomicAdd(&lh[d], 1);
            d = min(max(d4.y, 0), N - 1) - lo; if ((unsigned)d < (unsigned)span) atomicAdd(&lh[d], 1);
            d = min(max(d4.z, 0), N - 1) - lo; if ((unsigned)d < (unsigned)span) atomicAdd(&lh[d], 1);
            d = min(max(d4.w, 0), N - 1) - lo; if ((unsigned)d < (unsigned)span) atomicAdd(&lh[d], 1);
        }
        for (int e = e0 + nv * 4 + t; e < e1; e += 1024) {
            const int d = min(max(ei[E + e], 0), N - 1) - lo;
            if ((unsigned)d < (unsigned)span) atomicAdd(&lh[d], 1);
        }
    } else {
        for (int e = e0 + t; e < e1; e += 1024) {
            const int d = min(max(ei[E + e], 0), N - 1) - lo;
            if ((unsigned)d < (unsigned)span) atomicAdd(&lh[d], 1);
        }
    }
    __syncthreads();

    for (int i = t; i < span; i += 1024) countsC[(size_t)c * N + lo + i] = lh[i];
}

// ---------------------------------------------------------------------------
// QKV GEMM, persistent-W + XOR-swizzled LDS (R10-R12-verified).
//   acc += xh*wh + xh*wl + xl*wh    (xl*wl ~ 2^-17 dropped)
// ---------------------------------------------------------------------------
#define CVT_WRITE(buf, rr, cc, val) do {                                      \
    const float ff_[4] = {(val).x, (val).y, (val).z, (val).w};                \
    u16x4 h_, l_;                                                             \
    _Pragma("unroll")                                                         \
    for (int u_ = 0; u_ < 4; ++u_) {                                          \
        unsigned ub_ = __float_as_uint(ff_[u_]);                              \
        h_[u_] = (unsigned short)(ub_ >> 16);                                 \
        float rf_ = ff_[u_] - __uint_as_float(ub_ & 0xFFFF0000u);             \
        l_[u_] = (unsigned short)(__float_as_uint(rf_) >> 16);                \
    }                                                                         \
    const int so_ = (rr) * 64 + (((((cc) >> 1) ^ ((rr) & 7))) << 3)           \
                  + ((cc) & 1) * 4;                                           \
    *(u16x4*)&xs_hi[buf][so_] = h_;                                           \
    *(u16x4*)&xs_lo[buf][so_] = l_;                                           \
} while (0)

__global__ __launch_bounds__(768, 3) void qkv_mfma(
    const float* __restrict__ x,
    const float* __restrict__ Wq, const float* __restrict__ Wk,
    const float* __restrict__ Wv,
    const float* __restrict__ bq, const float* __restrict__ bk,
    const float* __restrict__ bv,
    float* __restrict__ q, float* __restrict__ k, float* __restrict__ v,
    int N, int ntiles)
{
    __shared__ unsigned short xs_hi[2][MB * 64];   // 2 x 8 KB, swizzled
    __shared__ unsigned short xs_lo[2][MB * 64];   // 2 x 8 KB, swizzled

    const int t    = threadIdx.x;
    const int lane = t & 63;
    const int w    = t >> 6;        // 0..11
    const int mat  = w >> 2;        // 0..2  (Q,K,V)
    const int ct   = w & 3;         // 16-col tile
    const int l15  = lane & 15;
    const int quad = lane >> 4;

    const float* Wm   = (mat == 0) ? Wq : (mat == 1) ? Wk : Wv;
    const float* bias = (mat == 0) ? bq : (mat == 1) ? bk : bv;
    float*       dst  = (mat == 0) ? q  : (mat == 1) ? k  : v;
    const int col = ct * 16 + l15;
    const float bb = bias[col];

    // ---- W preload: full-K B fragments in registers, split hi/lo in-reg ---
    bf16x8 Bh[8], Bl[8];
    #pragma unroll
    for (int u = 0; u < 8; ++u) {
        #pragma unroll
        for (int j = 0; j < 8; ++j) {
            const float f = Wm[(size_t)(u * 32 + quad * 8 + j) * H + col];
            const unsigned ub = __float_as_uint(f);
            Bh[u][j] = (short)(ub >> 16);
            const float rf = f - __uint_as_float(ub & 0xFFFF0000u);
            Bl[u][j] = (short)(__float_as_uint(rf) >> 16);
        }
    }

    // staging slots: 1024 float4 per chunk; thread t does slot t (always)
    // and slot t+768 (t<256).  (t+768)&15 == t&15 since 768 % 16 == 0.
    const int r0 = t >> 4;
    const int c0 = t & 15;
    const int r1 = (t + 768) >> 4;

    // swizzled read offsets (row & 7 == l15 & 7)
    const int swz = (l15 & 7);

    #pragma unroll 1
    for (int tile = blockIdx.x; tile < ntiles; tile += gridDim.x) {
        const int block0 = tile * MB;

        f32x4v acc[4];
        #pragma unroll
        for (int i = 0; i < 4; ++i) acc[i] = (f32x4v)0.f;

        // ---- prologue: chunk 0 into buffer 0 ----
        float4 pv0, pv1;
        pv0 = *(const float4*)(x + (size_t)min(block0 + r0, N - 1) * F + c0 * 4);
        if (t < 256)
            pv1 = *(const float4*)(x + (size_t)min(block0 + r1, N - 1) * F + c0 * 4);
        CVT_WRITE(0, r0, c0, pv0);
        if (t < 256) CVT_WRITE(0, r1, c0, pv1);

        #pragma unroll
        for (int c = 0; c < 4; ++c) {
            __syncthreads();          // buf[c&1] writes visible to all waves

            // issue next chunk's loads EARLY (consumed after the MFMAs)
            if (c < 3) {
                const int kb = (c + 1) * KC;
                pv0 = *(const float4*)(x + (size_t)min(block0 + r0, N - 1) * F + kb + c0 * 4);
                if (t < 256)
                    pv1 = *(const float4*)(x + (size_t)min(block0 + r1, N - 1) * F + kb + c0 * 4);
            }

            // MFMA burst on buf[c&1]; B frags from registers (u = c*2+sk)
            #pragma unroll
            for (int sk = 0; sk < 2; ++sk) {
                const int u = c * 2 + sk;
                #pragma unroll
                for (int mt = 0; mt < 4; ++mt) {
                    const int row = mt * 16 + l15;
                    const int ao  = row * 64 + (((sk * 4 + quad) ^ swz) << 3);
                    const bf16x8 ah = *(const bf16x8*)&xs_hi[c & 1][ao];
                    const bf16x8 al = *(const bf16x8*)&xs_lo[c & 1][ao];
                    f32x4v a = acc[mt];
                    a = __builtin_amdgcn_mfma_f32_16x16x32_bf16(ah, Bh[u], a, 0, 0, 0);
                    a = __builtin_amdgcn_mfma_f32_16x16x32_bf16(ah, Bl[u], a, 0, 0, 0);
                    a = __builtin_amdgcn_mfma_f32_16x16x32_bf16(al, Bh[u], a, 0, 0, 0);
                    acc[mt] = a;
                }
            }

            // convert + write next chunk into the other buffer (WAR-safe:
            // buf[nxt] last read in chunk c-1, all waves past top-of-c barrier)
            if (c < 3) {
                const int nb = (c & 1) ^ 1;
                CVT_WRITE(nb, r0, c0, pv0);
                if (t < 256) CVT_WRITE(nb, r1, c0, pv1);
            }
        }

        // epilogue: C layout col = lane&15, row = quad*4 + reg (m89-verified)
        #pragma unroll
        for (int mt = 0; mt < 4; ++mt) {
            #pragma unroll
            for (int r = 0; r < 4; ++r) {
                const int node = block0 + mt * 16 + quad * 4 + r;
                if (node < N)
                    dst[(size_t)node * H + col] = acc[mt][r] + bb;
            }
        }
    }
}

// ---------------------------------------------------------------------------
// Scan phase A/B/C: exclusive scan of padded (x4) per-node counts.
// scanA sums the NCHUNK per-chunk histogram copies; scanC carves each
// node's slot range into NCHUNK per-chunk sub-ranges (cursorC) so reorder
// can allocate positions with LDS atomics only.
// ---------------------------------------------------------------------------
__global__ __launch_bounds__(256) void scanA(
    const int* __restrict__ countsC, int* __restrict__ counts,
    int* __restrict__ offsets, int* __restrict__ bsum, int n)
{
    __shared__ int ps[256];
    const int t = threadIdx.x;
    const int i0 = blockIdx.x * SCB + t * 8;
    int loc[8];
    int s = 0;
    #pragma unroll
    for (int u = 0; u < 8; ++u) {
        int i = i0 + u;
        int c = 0;
        if (i < n) {
            #pragma unroll
            for (int p = 0; p < NCHUNK; ++p) c += countsC[(size_t)p * n + i];
            counts[i] = c;
            c = (c + 3) & ~3;
        }
        loc[u] = s; s += c;
    }
    ps[t] = s;
    __syncthreads();
    for (int off = 1; off < 256; off <<= 1) {
        int a = (t >= off) ? ps[t - off] : 0;
        __syncthreads();
        ps[t] += a;
        __syncthreads();
    }
    const int base = ps[t] - s;
    #pragma unroll
    for (int u = 0; u < 8; ++u) {
        int i = i0 + u;
        if (i < n) offsets[i] = base + loc[u];
    }
    if (t == 255) bsum[blockIdx.x] = ps[255];
}

__global__ void scanB(int* __restrict__ bsum, int nb)
{
    // single-wave shuffle exclusive scan (nb <= 64)
    const int t = threadIdx.x;
    int v = (t < nb) ? bsum[t] : 0;
    int inc = v;
    #pragma unroll
    for (int off = 1; off < 64; off <<= 1) {
        int u = __shfl_up(inc, off, 64);
        if (t >= off) inc += u;
    }
    if (t < nb) bsum[t] = inc - v;   // exclusive
}

__global__ __launch_bounds__(256) void scanC(
    const int* __restrict__ bsum, const int* __restrict__ countsC,
    int* __restrict__ offsets, int* __restrict__ cursorC, int n)
{
    const int i0 = blockIdx.x * SCB + threadIdx.x * 8;
    const int add = bsum[blockIdx.x];
    #pragma unroll
    for (int u = 0; u < 8; ++u) {
        int i = i0 + u;
        if (i < n) {
            int o = offsets[i] + add;
            offsets[i] = o;
            #pragma unroll
            for (int p = 0; p < NCHUNK; ++p) {
                cursorC[(size_t)p * n + i] = o;   // start of chunk p's sub-range
                o += countsC[(size_t)p * n + i];
            }
        }
    }
}

// ---------------------------------------------------------------------------
// Reorder v3: LDS-cursor scatter, ZERO global atomics.  R12 post-mortem:
// 800K global returning atomics were the latency chain (41us for ~9us of
// traffic; VALU 6.7% at 64% occupancy).  Same fix that worked for hist:
// span cursor slice fits LDS (25 KB); block (p,c) loads cursorC[c]'s span
// slice, allocates positions with LDS atomicAdd, scatter-writes epack.
// (node,chunk) sub-ranges are disjoint by construction -> race-free.
// pack = src(16b) | seg(8b)<<16.
// ---------------------------------------------------------------------------
__global__ __launch_bounds__(1024) void reorder_kernel(
    const int* __restrict__ ei, const int* __restrict__ batch,
    const int* __restrict__ cursorC, unsigned* __restrict__ epack,
    int E, int N, int nspan)
{
    __shared__ int lcur[NSPAN_MAX];
    const int p  = blockIdx.x & 7;
    const int c  = blockIdx.x >> 3;
    const int lo = p * nspan;
    const int span = min(N - lo, nspan);
    const int t = threadIdx.x;

    for (int i = t; i < span; i += 1024) lcur[i] = cursorC[(size_t)c * N + lo + i];
    __syncthreads();

    const int epc = (E + NCHUNK - 1) / NCHUNK;
    const int e0 = c * epc;
    const int e1 = min(E, e0 + epc);

    if (((E | e0) & 3) == 0) {               // 16B-aligned vector path
        const int nv = (e1 - e0) >> 2;
        for (int i = t; i < nv; i += 1024) {
            const int eb = e0 + i * 4;
            const int4 d4 = *(const int4*)(ei + E + eb);
            const int dd[4] = {d4.x, d4.y, d4.z, d4.w};
            #pragma unroll
            for (int u = 0; u < 4; ++u) {
                const int d = min(max(dd[u], 0), N - 1) - lo;
                if ((unsigned)d < (unsigned)span) {
                    const int pos = atomicAdd(&lcur[d], 1);
                    const int src = min(max(ei[eb + u], 0), N - 1);
                    const int seg = min(max(batch[src], 0), NSEG - 1);
                    epack[pos] = (unsigned)src | ((unsigned)seg << 16);
                }
            }
        }
        for (int e = e0 + nv * 4 + t; e < e1; e += 1024) {
            const int d = min(max(ei[E + e], 0), N - 1) - lo;
            if ((unsigned)d < (unsigned)span) {
                const int pos = atomicAdd(&lcur[d], 1);
                const int src = min(max(ei[e], 0), N - 1);
                const int seg = min(max(batch[src], 0), NSEG - 1);
                epack[pos] = (unsigned)src | ((unsigned)seg << 16);
            }
        }
    } else {
        for (int e = e0 + t; e < e1; e += 1024) {
            const int d = min(max(ei[E + e], 0), N - 1) - lo;
            if ((unsigned)d < (unsigned)span) {
                const int pos = atomicAdd(&lcur[d], 1);
                const int src = min(max(ei[e], 0), N - 1);
                const int seg = min(max(batch[src], 0), NSEG - 1);
                epack[pos] = (unsigned)src | ((unsigned)seg << 16);
            }
        }
    }
}

// ---------------------------------------------------------------------------
// Score v2: 4-edge ILP batches (R12-verified: out of top-5).
// ---------------------------------------------------------------------------
__global__ __launch_bounds__(256) void score_kernel(
    const float* __restrict__ q, const float* __restrict__ k,
    const unsigned* __restrict__ epack,
    const int* __restrict__ offsets, const int* __restrict__ counts,
    float* __restrict__ exps, float* __restrict__ denom8, int N)
{
    __shared__ float sden[NSEG];
    const int t = threadIdx.x;
    sden[t] = 0.f;
    __syncthreads();

    const int lane16 = t & 15;
    const int grp    = (t >> 4) & 3;
    const int wave   = t >> 6;
    const int nwaves = gridDim.x * 4;

    const float4* q4 = (const float4*)q;
    const float4* k4 = (const float4*)k;

    for (int n = blockIdx.x * 4 + wave; n < N; n += nwaves) {
        const int off = offsets[n];
        const int cnt = counts[n];
        if (cnt == 0) continue;
        const float4 qv = q4[(size_t)n * 16 + lane16];
        for (int i0 = grp * 4; i0 < cnt; i0 += 16) {
            const uint4 pp = *(const uint4*)(epack + off + i0);   // 16B-aligned
            const unsigned pk[4] = {pp.x, pp.y, pp.z, pp.w};
            const int rem = cnt - i0;
            float4 kv[4];
            #pragma unroll
            for (int u = 0; u < 4; ++u) {
                const int src = min((int)(pk[u] & 0xFFFF), N - 1);
                kv[u] = k4[(size_t)src * 16 + lane16];
            }
            float d[4];
            #pragma unroll
            for (int u = 0; u < 4; ++u) {
                float dd = kv[u].x * qv.x + kv[u].y * qv.y
                         + kv[u].z * qv.z + kv[u].w * qv.w;
                dd += __shfl_xor(dd, 1, 64);
                dd += __shfl_xor(dd, 2, 64);
                dd += __shfl_xor(dd, 4, 64);
                dd += __shfl_xor(dd, 8, 64);
                d[u] = dd;
            }
            if (lane16 == 0) {
                #pragma unroll
                for (int u = 0; u < 4; ++u) {
                    if (u < rem) {
                        const float ex = __expf(d[u] * 0.125f);
                        exps[off + i0 + u] = ex;
                        atomicAdd(&sden[(pk[u] >> 16) & 255], ex);
                    }
                }
            }
        }
    }
    __syncthreads();
    float ds = sden[t];
    if (ds != 0.f) atomicAdd(&denom8[(blockIdx.x & 7) * NSEG + t], ds);
}

// ---------------------------------------------------------------------------
// Accumulate: one wave per dst node, lane = feature, register accumulator,
// zero atomics.  LDS reciprocal table built by summing the 8 denom copies.
// ---------------------------------------------------------------------------
__global__ __launch_bounds__(256) void accum_kernel(
    const float* __restrict__ v, const float* __restrict__ exps,
    const unsigned* __restrict__ epack,
    const int* __restrict__ offsets, const int* __restrict__ counts,
    const float* __restrict__ denom8, float* __restrict__ out, int N)
{
    __shared__ float rden[NSEG];
    const int t = threadIdx.x;
    {
        float dsum = 0.f;
        #pragma unroll
        for (int p = 0; p < 8; ++p) dsum += denom8[p * NSEG + t];
        rden[t] = 1.0f / (dsum + 1e-6f);
    }
    __syncthreads();

    const int lane = t & 63;
    const int wave = t >> 6;
    const int n = blockIdx.x * 4 + wave;
    if (n >= N) return;

    const int off = offsets[n];
    const int cnt = counts[n];

    float acc = 0.f;
    int i = 0;
    for (; i + 8 <= cnt; i += 8) {
        const uint4  pa = *(const uint4*)(epack + off + i);
        const uint4  pb = *(const uint4*)(epack + off + i + 4);
        const float4 ea = *(const float4*)(exps + off + i);
        const float4 eb = *(const float4*)(exps + off + i + 4);
        const float v0 = v[(size_t)(pa.x & 0xFFFF) * H + lane];
        const float v1 = v[(size_t)(pa.y & 0xFFFF) * H + lane];
        const float v2 = v[(size_t)(pa.z & 0xFFFF) * H + lane];
        const float v3 = v[(size_t)(pa.w & 0xFFFF) * H + lane];
        const float v4_ = v[(size_t)(pb.x & 0xFFFF) * H + lane];
        const float v5 = v[(size_t)(pb.y & 0xFFFF) * H + lane];
        const float v6 = v[(size_t)(pb.z & 0xFFFF) * H + lane];
        const float v7 = v[(size_t)(pb.w & 0xFFFF) * H + lane];
        acc = fmaf(v0, ea.x * rden[(pa.x >> 16) & 255], acc);
        acc = fmaf(v1, ea.y * rden[(pa.y >> 16) & 255], acc);
        acc = fmaf(v2, ea.z * rden[(pa.z >> 16) & 255], acc);
        acc = fmaf(v3, ea.w * rden[(pa.w >> 16) & 255], acc);
        acc = fmaf(v4_, eb.x * rden[(pb.x >> 16) & 255], acc);
        acc = fmaf(v5, eb.y * rden[(pb.y >> 16) & 255], acc);
        acc = fmaf(v6, eb.z * rden[(pb.z >> 16) & 255], acc);
        acc = fmaf(v7, eb.w * rden[(pb.w >> 16) & 255], acc);
    }
    for (; i + 4 <= cnt; i += 4) {
        const uint4  pp = *(const uint4*)(epack + off + i);
        const float4 ee = *(const float4*)(exps + off + i);
        const float v0 = v[(size_t)(pp.x & 0xFFFF) * H + lane];
        const float v1 = v[(size_t)(pp.y & 0xFFFF) * H + lane];
        const float v2 = v[(size_t)(pp.z & 0xFFFF) * H + lane];
        const float v3 = v[(size_t)(pp.w & 0xFFFF) * H + lane];
        acc = fmaf(v0, ee.x * rden[(pp.x >> 16) & 255], acc);
        acc = fmaf(v1, ee.y * rden[(pp.y >> 16) & 255], acc);
        acc = fmaf(v2, ee.z * rden[(pp.z >> 16) & 255], acc);
        acc = fmaf(v3, ee.w * rden[(pp.w >> 16) & 255], acc);
    }
    for (; i < cnt; ++i) {
        const unsigned p = epack[off + i];
        acc = fmaf(v[(size_t)(p & 0xFFFF) * H + lane],
                   exps[off + i] * rden[(p >> 16) & 255], acc);
    }
    out[(size_t)n * H + lane] = acc;
}

extern "C" void kernel_launch(void* const* d_in, const int* in_sizes, int n_in,
                              void* d_out, int out_size, void* d_ws, size_t ws_size,
                              hipStream_t stream)
{
    const float* x   = (const float*)d_in[0];
    const float* Wq  = (const float*)d_in[1];
    const float* bq  = (const float*)d_in[2];
    const float* Wk  = (const float*)d_in[3];
    const float* bk  = (const float*)d_in[4];
    const float* Wv  = (const float*)d_in[5];
    const float* bv  = (const float*)d_in[6];
    const int* ei    = (const int*)d_in[7];
    const int* batch = (const int*)d_in[8];

    const int N = in_sizes[8];        // 50000
    const int E = in_sizes[7] / 2;    // 800000
    const int EP = E + 3 * N + 16;    // padded edge-slot capacity

    float*    q       = (float*)d_ws;
    float*    k       = q + (size_t)N * H;
    float*    v       = k + (size_t)N * H;
    float*    exps    = v + (size_t)N * H;
    unsigned* epack   = (unsigned*)(exps + EP);
    int*      counts  = (int*)(epack + EP);
    int*      offsets = counts + N;
    int*      bsum    = offsets + N;
    float*    denom8  = (float*)(bsum + 64);
    int*      countsC = (int*)(denom8 + 8 * NSEG);       // NCHUNK*N ints
    int*      cursorC = countsC + (size_t)NCHUNK * N;    // NCHUNK*N ints

    hipMemsetAsync(denom8, 0, 8 * NSEG * sizeof(float), stream);

    const int NT    = (N + MB - 1) / MB;     // 782 row tiles
    const int nspan = (N + 7) / 8;           // dst-range span per class
    const int NBSC  = (N + SCB - 1) / SCB;   // 25 scan blocks

    hist_kernel<<<8 * NCHUNK, 1024, 0, stream>>>(ei, countsC, N, E, nspan);

    qkv_mfma<<<256, 768, 0, stream>>>(
        x, Wq, Wk, Wv, bq, bk, bv, q, k, v, N, NT);

    scanA<<<NBSC, 256, 0, stream>>>(countsC, counts, offsets, bsum, N);
    scanB<<<1, 64, 0, stream>>>(bsum, NBSC);
    scanC<<<NBSC, 256, 0, stream>>>(bsum, countsC, offsets, cursorC, N);

    reorder_kernel<<<8 * NCHUNK, 1024, 0, stream>>>(
        ei, batch, cursorC, epack, E, N, nspan);

    score_kernel<<<2048, 256, 0, stream>>>(
        q, k, epack, offsets, counts, exps, denom8, N);

    accum_kernel<<<(N + 3) / 4, 256, 0, stream>>>(
        v, exps, epack, offsets, counts, denom8, (float*)d_out, N);
}

// Round 14
// 261.913 us; speedup vs baseline: 1.0674x; 1.0674x over previous
//
#include <hip/hip_runtime.h>

#define H    64
#define F    256
#define NSEG 256
#define SCB  2048   // scan elements per block
#define MB   64     // qkv node rows per tile
#define KC   64     // qkv K chunk
#define NSPAN_MAX 8192

typedef float          f32x4v __attribute__((ext_vector_type(4)));
typedef short          bf16x8 __attribute__((ext_vector_type(8)));
typedef unsigned short u16x4  __attribute__((ext_vector_type(4)));

// ---------------------------------------------------------------------------
// In-degree histogram: LDS-privatized, zero global atomics (R9/R12-verified).
// Grid = 8 spans x 8 chunks; LDS histogram per block; non-atomic flush to
// counts8[chunk]; scanA sums the 8 copies.
// ---------------------------------------------------------------------------
__global__ __launch_bounds__(1024) void hist8_kernel(
    const int* __restrict__ ei, int* __restrict__ counts8,
    int N, int E, int nspan)
{
    __shared__ int lh[NSPAN_MAX];
    const int p  = blockIdx.x & 7;           // span class
    const int c  = blockIdx.x >> 3;          // edge chunk 0..7
    const int lo = p * nspan;
    const int span = min(N - lo, nspan);
    const int t = threadIdx.x;

    for (int i = t; i < span; i += 1024) lh[i] = 0;
    __syncthreads();

    const int epc = (E + 7) >> 3;            // edges per chunk
    const int e0 = c * epc;
    const int e1 = min(E, e0 + epc);

    if (((E | e0) & 3) == 0) {               // 16B-aligned vector path
        const int nv = (e1 - e0) >> 2;
        for (int i = t; i < nv; i += 1024) {
            const int4 d4 = *(const int4*)(ei + E + e0 + i * 4);
            int d;
            d = min(max(d4.x, 0), N - 1) - lo; if ((unsigned)d < (unsigned)span) atomicAdd(&lh[d], 1);
            d = min(max(d4.y, 0), N - 1) - lo; if ((unsigned)d < (unsigned)span) atomicAdd(&lh[d], 1);
            d = min(max(d4.z, 0), N - 1) - lo; if ((unsigned)d < (unsigned)span) atomicAdd(&lh[d], 1);
            d = min(max(d4.w, 0), N - 1) - lo; if ((unsigned)d < (unsigned)span) atomicAdd(&lh[d], 1);
        }
        for (int e = e0 + nv * 4 + t; e < e1; e += 1024) {
            const int d = min(max(ei[E + e], 0), N - 1) - lo;
            if ((unsigned)d < (unsigned)span) atomicAdd(&lh[d], 1);
        }
    } else {
        for (int e = e0 + t; e < e1; e += 1024) {
            const int d = min(max(ei[E + e], 0), N - 1) - lo;
            if ((unsigned)d < (unsigned)span) atomicAdd(&lh[d], 1);
        }
    }
    __syncthreads();

    for (int i = t; i < span; i += 1024) counts8[(size_t)c * N + lo + i] = lh[i];
}

// ---------------------------------------------------------------------------
// QKV GEMM, persistent-W + XOR-swizzled LDS (R10-R12-verified).
//   acc += xh*wh + xh*wl + xl*wh    (xl*wl ~ 2^-17 dropped)
// ---------------------------------------------------------------------------
#define CVT_WRITE(buf, rr, cc, val) do {                                      \
    const float ff_[4] = {(val).x, (val).y, (val).z, (val).w};                \
    u16x4 h_, l_;                                                             \
    _Pragma("unroll")                                                         \
    for (int u_ = 0; u_ < 4; ++u_) {                                          \
        unsigned ub_ = __float_as_uint(ff_[u_]);                              \
        h_[u_] = (unsigned short)(ub_ >> 16);                                 \
        float rf_ = ff_[u_] - __uint_as_float(ub_ & 0xFFFF0000u);             \
        l_[u_] = (unsigned short)(__float_as_uint(rf_) >> 16);                \
    }                                                                         \
    const int so_ = (rr) * 64 + (((((cc) >> 1) ^ ((rr) & 7))) << 3)           \
                  + ((cc) & 1) * 4;                                           \
    *(u16x4*)&xs_hi[buf][so_] = h_;                                           \
    *(u16x4*)&xs_lo[buf][so_] = l_;                                           \
} while (0)

__global__ __launch_bounds__(768, 3) void qkv_mfma(
    const float* __restrict__ x,
    const float* __restrict__ Wq, const float* __restrict__ Wk,
    const float* __restrict__ Wv,
    const float* __restrict__ bq, const float* __restrict__ bk,
    const float* __restrict__ bv,
    float* __restrict__ q, float* __restrict__ k, float* __restrict__ v,
    int N, int ntiles)
{
    __shared__ unsigned short xs_hi[2][MB * 64];   // 2 x 8 KB, swizzled
    __shared__ unsigned short xs_lo[2][MB * 64];   // 2 x 8 KB, swizzled

    const int t    = threadIdx.x;
    const int lane = t & 63;
    const int w    = t >> 6;        // 0..11
    const int mat  = w >> 2;        // 0..2  (Q,K,V)
    const int ct   = w & 3;         // 16-col tile
    const int l15  = lane & 15;
    const int quad = lane >> 4;

    const float* Wm   = (mat == 0) ? Wq : (mat == 1) ? Wk : Wv;
    const float* bias = (mat == 0) ? bq : (mat == 1) ? bk : bv;
    float*       dst  = (mat == 0) ? q  : (mat == 1) ? k  : v;
    const int col = ct * 16 + l15;
    const float bb = bias[col];

    // ---- W preload: full-K B fragments in registers, split hi/lo in-reg ---
    bf16x8 Bh[8], Bl[8];
    #pragma unroll
    for (int u = 0; u < 8; ++u) {
        #pragma unroll
        for (int j = 0; j < 8; ++j) {
            const float f = Wm[(size_t)(u * 32 + quad * 8 + j) * H + col];
            const unsigned ub = __float_as_uint(f);
            Bh[u][j] = (short)(ub >> 16);
            const float rf = f - __uint_as_float(ub & 0xFFFF0000u);
            Bl[u][j] = (short)(__float_as_uint(rf) >> 16);
        }
    }

    // staging slots: 1024 float4 per chunk; thread t does slot t (always)
    // and slot t+768 (t<256).  (t+768)&15 == t&15 since 768 % 16 == 0.
    const int r0 = t >> 4;
    const int c0 = t & 15;
    const int r1 = (t + 768) >> 4;

    // swizzled read offsets (row & 7 == l15 & 7)
    const int swz = (l15 & 7);

    #pragma unroll 1
    for (int tile = blockIdx.x; tile < ntiles; tile += gridDim.x) {
        const int block0 = tile * MB;

        f32x4v acc[4];
        #pragma unroll
        for (int i = 0; i < 4; ++i) acc[i] = (f32x4v)0.f;

        // ---- prologue: chunk 0 into buffer 0 ----
        float4 pv0, pv1;
        pv0 = *(const float4*)(x + (size_t)min(block0 + r0, N - 1) * F + c0 * 4);
        if (t < 256)
            pv1 = *(const float4*)(x + (size_t)min(block0 + r1, N - 1) * F + c0 * 4);
        CVT_WRITE(0, r0, c0, pv0);
        if (t < 256) CVT_WRITE(0, r1, c0, pv1);

        #pragma unroll
        for (int c = 0; c < 4; ++c) {
            __syncthreads();          // buf[c&1] writes visible to all waves

            // issue next chunk's loads EARLY (consumed after the MFMAs)
            if (c < 3) {
                const int kb = (c + 1) * KC;
                pv0 = *(const float4*)(x + (size_t)min(block0 + r0, N - 1) * F + kb + c0 * 4);
                if (t < 256)
                    pv1 = *(const float4*)(x + (size_t)min(block0 + r1, N - 1) * F + kb + c0 * 4);
            }

            // MFMA burst on buf[c&1]; B frags from registers (u = c*2+sk)
            #pragma unroll
            for (int sk = 0; sk < 2; ++sk) {
                const int u = c * 2 + sk;
                #pragma unroll
                for (int mt = 0; mt < 4; ++mt) {
                    const int row = mt * 16 + l15;
                    const int ao  = row * 64 + (((sk * 4 + quad) ^ swz) << 3);
                    const bf16x8 ah = *(const bf16x8*)&xs_hi[c & 1][ao];
                    const bf16x8 al = *(const bf16x8*)&xs_lo[c & 1][ao];
                    f32x4v a = acc[mt];
                    a = __builtin_amdgcn_mfma_f32_16x16x32_bf16(ah, Bh[u], a, 0, 0, 0);
                    a = __builtin_amdgcn_mfma_f32_16x16x32_bf16(ah, Bl[u], a, 0, 0, 0);
                    a = __builtin_amdgcn_mfma_f32_16x16x32_bf16(al, Bh[u], a, 0, 0, 0);
                    acc[mt] = a;
                }
            }

            // convert + write next chunk into the other buffer (WAR-safe:
            // buf[nxt] last read in chunk c-1, all waves past top-of-c barrier)
            if (c < 3) {
                const int nb = (c & 1) ^ 1;
                CVT_WRITE(nb, r0, c0, pv0);
                if (t < 256) CVT_WRITE(nb, r1, c0, pv1);
            }
        }

        // epilogue: C layout col = lane&15, row = quad*4 + reg (m89-verified)
        #pragma unroll
        for (int mt = 0; mt < 4; ++mt) {
            #pragma unroll
            for (int r = 0; r < 4; ++r) {
                const int node = block0 + mt * 16 + quad * 4 + r;
                if (node < N)
                    dst[(size_t)node * H + col] = acc[mt][r] + bb;
            }
        }
    }
}

// ---------------------------------------------------------------------------
// Scan phase A/B/C: exclusive scan of padded (x4) per-node counts.
// scanA sums the 8 per-chunk histogram copies and emits merged counts.
// ---------------------------------------------------------------------------
__global__ __launch_bounds__(256) void scanA(
    const int* __restrict__ counts8, int* __restrict__ counts,
    int* __restrict__ offsets, int* __restrict__ bsum, int n)
{
    __shared__ int ps[256];
    const int t = threadIdx.x;
    const int i0 = blockIdx.x * SCB + t * 8;
    int loc[8];
    int s = 0;
    #pragma unroll
    for (int u = 0; u < 8; ++u) {
        int i = i0 + u;
        int c = 0;
        if (i < n) {
            #pragma unroll
            for (int p = 0; p < 8; ++p) c += counts8[(size_t)p * n + i];
            counts[i] = c;
            c = (c + 3) & ~3;
        }
        loc[u] = s; s += c;
    }
    ps[t] = s;
    __syncthreads();
    for (int off = 1; off < 256; off <<= 1) {
        int a = (t >= off) ? ps[t - off] : 0;
        __syncthreads();
        ps[t] += a;
        __syncthreads();
    }
    const int base = ps[t] - s;
    #pragma unroll
    for (int u = 0; u < 8; ++u) {
        int i = i0 + u;
        if (i < n) offsets[i] = base + loc[u];
    }
    if (t == 255) bsum[blockIdx.x] = ps[255];
}

__global__ void scanB(int* __restrict__ bsum, int nb)
{
    // single-wave shuffle exclusive scan (nb <= 64)
    const int t = threadIdx.x;
    int v = (t < nb) ? bsum[t] : 0;
    int inc = v;
    #pragma unroll
    for (int off = 1; off < 64; off <<= 1) {
        int u = __shfl_up(inc, off, 64);
        if (t >= off) inc += u;
    }
    if (t < nb) bsum[t] = inc - v;   // exclusive
}

__global__ __launch_bounds__(256) void scanC(
    const int* __restrict__ bsum, int* __restrict__ offsets,
    int* __restrict__ cursor, int n)
{
    const int i0 = blockIdx.x * SCB + threadIdx.x * 8;
    const int add = bsum[blockIdx.x];
    #pragma unroll
    for (int u = 0; u < 8; ++u) {
        int i = i0 + u;
        if (i < n) { int o = offsets[i] + add; offsets[i] = o; cursor[i] = o; }
    }
}

// ---------------------------------------------------------------------------
// Reorder edges into dst-node order, dst-range partitioned by blockIdx&7
// (R9/R12-measured-best shape) with 8 edges/thread (two aligned int4 loads,
// 8 independent atomic->store chains).  R13 post-mortem: LDS-cursor variant
// regressed (128-block grid = half the device idle); the R12 shape is best,
// and its 41us is atomic LATENCY -> attack with deeper ILP, the same lever
// that cut score 41->~30 in R12.  pack = src(16b) | seg(8b)<<16.
// ---------------------------------------------------------------------------
__global__ __launch_bounds__(256) void reorder_kernel(
    const int* __restrict__ ei, const int* __restrict__ batch,
    int* __restrict__ cursor, unsigned* __restrict__ epack,
    int E, int N, int nspan)
{
    const int p  = blockIdx.x & 7;
    const int ci = blockIdx.x >> 3;
    const int lo = p * nspan;
    const int hi = min(N, lo + nspan);
    const int e0 = ci * 2048 + threadIdx.x * 8;

    int d[8];
    if (e0 + 7 < E) {
        const int4 a = *(const int4*)(ei + E + e0);
        const int4 b = *(const int4*)(ei + E + e0 + 4);
        d[0] = a.x; d[1] = a.y; d[2] = a.z; d[3] = a.w;
        d[4] = b.x; d[5] = b.y; d[6] = b.z; d[7] = b.w;
    } else {
        #pragma unroll
        for (int u = 0; u < 8; ++u)
            d[u] = (e0 + u < E) ? ei[E + e0 + u] : -1;   // -1: never in span
    }

    #pragma unroll
    for (int u = 0; u < 8; ++u) {
        const int dst = min(max(d[u], 0), N - 1);
        if (d[u] >= 0 && dst >= lo && dst < hi) {
            int src = ei[e0 + u];
            src = min(max(src, 0), N - 1);
            int seg = batch[src];
            seg = min(max(seg, 0), NSEG - 1);
            const int pos = atomicAdd(&cursor[dst], 1);
            epack[pos] = (unsigned)src | ((unsigned)seg << 16);
        }
    }
}

// ---------------------------------------------------------------------------
// Score v2: 4-edge ILP batches (R12-verified: out of top-5).
// ---------------------------------------------------------------------------
__global__ __launch_bounds__(256) void score_kernel(
    const float* __restrict__ q, const float* __restrict__ k,
    const unsigned* __restrict__ epack,
    const int* __restrict__ offsets, const int* __restrict__ counts,
    float* __restrict__ exps, float* __restrict__ denom8, int N)
{
    __shared__ float sden[NSEG];
    const int t = threadIdx.x;
    sden[t] = 0.f;
    __syncthreads();

    const int lane16 = t & 15;
    const int grp    = (t >> 4) & 3;
    const int wave   = t >> 6;
    const int nwaves = gridDim.x * 4;

    const float4* q4 = (const float4*)q;
    const float4* k4 = (const float4*)k;

    for (int n = blockIdx.x * 4 + wave; n < N; n += nwaves) {
        const int off = offsets[n];
        const int cnt = counts[n];
        if (cnt == 0) continue;
        const float4 qv = q4[(size_t)n * 16 + lane16];
        for (int i0 = grp * 4; i0 < cnt; i0 += 16) {
            const uint4 pp = *(const uint4*)(epack + off + i0);   // 16B-aligned
            const unsigned pk[4] = {pp.x, pp.y, pp.z, pp.w};
            const int rem = cnt - i0;
            float4 kv[4];
            #pragma unroll
            for (int u = 0; u < 4; ++u) {
                const int src = min((int)(pk[u] & 0xFFFF), N - 1);
                kv[u] = k4[(size_t)src * 16 + lane16];
            }
            float d[4];
            #pragma unroll
            for (int u = 0; u < 4; ++u) {
                float dd = kv[u].x * qv.x + kv[u].y * qv.y
                         + kv[u].z * qv.z + kv[u].w * qv.w;
                dd += __shfl_xor(dd, 1, 64);
                dd += __shfl_xor(dd, 2, 64);
                dd += __shfl_xor(dd, 4, 64);
                dd += __shfl_xor(dd, 8, 64);
                d[u] = dd;
            }
            if (lane16 == 0) {
                #pragma unroll
                for (int u = 0; u < 4; ++u) {
                    if (u < rem) {
                        const float ex = __expf(d[u] * 0.125f);
                        exps[off + i0 + u] = ex;
                        atomicAdd(&sden[(pk[u] >> 16) & 255], ex);
                    }
                }
            }
        }
    }
    __syncthreads();
    float ds = sden[t];
    if (ds != 0.f) atomicAdd(&denom8[(blockIdx.x & 7) * NSEG + t], ds);
}

// ---------------------------------------------------------------------------
// Accumulate: one wave per dst node, lane = feature, register accumulator,
// zero atomics.  LDS reciprocal table built by summing the 8 denom copies.
// ---------------------------------------------------------------------------
__global__ __launch_bounds__(256) void accum_kernel(
    const float* __restrict__ v, const float* __restrict__ exps,
    const unsigned* __restrict__ epack,
    const int* __restrict__ offsets, const int* __restrict__ counts,
    const float* __restrict__ denom8, float* __restrict__ out, int N)
{
    __shared__ float rden[NSEG];
    const int t = threadIdx.x;
    {
        float dsum = 0.f;
        #pragma unroll
        for (int p = 0; p < 8; ++p) dsum += denom8[p * NSEG + t];
        rden[t] = 1.0f / (dsum + 1e-6f);
    }
    __syncthreads();

    const int lane = t & 63;
    const int wave = t >> 6;
    const int n = blockIdx.x * 4 + wave;
    if (n >= N) return;

    const int off = offsets[n];
    const int cnt = counts[n];

    float acc = 0.f;
    int i = 0;
    for (; i + 8 <= cnt; i += 8) {
        const uint4  pa = *(const uint4*)(epack + off + i);
        const uint4  pb = *(const uint4*)(epack + off + i + 4);
        const float4 ea = *(const float4*)(exps + off + i);
        const float4 eb = *(const float4*)(exps + off + i + 4);
        const float v0 = v[(size_t)(pa.x & 0xFFFF) * H + lane];
        const float v1 = v[(size_t)(pa.y & 0xFFFF) * H + lane];
        const float v2 = v[(size_t)(pa.z & 0xFFFF) * H + lane];
        const float v3 = v[(size_t)(pa.w & 0xFFFF) * H + lane];
        const float v4_ = v[(size_t)(pb.x & 0xFFFF) * H + lane];
        const float v5 = v[(size_t)(pb.y & 0xFFFF) * H + lane];
        const float v6 = v[(size_t)(pb.z & 0xFFFF) * H + lane];
        const float v7 = v[(size_t)(pb.w & 0xFFFF) * H + lane];
        acc = fmaf(v0, ea.x * rden[(pa.x >> 16) & 255], acc);
        acc = fmaf(v1, ea.y * rden[(pa.y >> 16) & 255], acc);
        acc = fmaf(v2, ea.z * rden[(pa.z >> 16) & 255], acc);
        acc = fmaf(v3, ea.w * rden[(pa.w >> 16) & 255], acc);
        acc = fmaf(v4_, eb.x * rden[(pb.x >> 16) & 255], acc);
        acc = fmaf(v5, eb.y * rden[(pb.y >> 16) & 255], acc);
        acc = fmaf(v6, eb.z * rden[(pb.z >> 16) & 255], acc);
        acc = fmaf(v7, eb.w * rden[(pb.w >> 16) & 255], acc);
    }
    for (; i + 4 <= cnt; i += 4) {
        const uint4  pp = *(const uint4*)(epack + off + i);
        const float4 ee = *(const float4*)(exps + off + i);
        const float v0 = v[(size_t)(pp.x & 0xFFFF) * H + lane];
        const float v1 = v[(size_t)(pp.y & 0xFFFF) * H + lane];
        const float v2 = v[(size_t)(pp.z & 0xFFFF) * H + lane];
        const float v3 = v[(size_t)(pp.w & 0xFFFF) * H + lane];
        acc = fmaf(v0, ee.x * rden[(pp.x >> 16) & 255], acc);
        acc = fmaf(v1, ee.y * rden[(pp.y >> 16) & 255], acc);
        acc = fmaf(v2, ee.z * rden[(pp.z >> 16) & 255], acc);
        acc = fmaf(v3, ee.w * rden[(pp.w >> 16) & 255], acc);
    }
    for (; i < cnt; ++i) {
        const unsigned p = epack[off + i];
        acc = fmaf(v[(size_t)(p & 0xFFFF) * H + lane],
                   exps[off + i] * rden[(p >> 16) & 255], acc);
    }
    out[(size_t)n * H + lane] = acc;
}

extern "C" void kernel_launch(void* const* d_in, const int* in_sizes, int n_in,
                              void* d_out, int out_size, void* d_ws, size_t ws_size,
                              hipStream_t stream)
{
    const float* x   = (const float*)d_in[0];
    const float* Wq  = (const float*)d_in[1];
    const float* bq  = (const float*)d_in[2];
    const float* Wk  = (const float*)d_in[3];
    const float* bk  = (const float*)d_in[4];
    const float* Wv  = (const float*)d_in[5];
    const float* bv  = (const float*)d_in[6];
    const int* ei    = (const int*)d_in[7];
    const int* batch = (const int*)d_in[8];

    const int N = in_sizes[8];        // 50000
    const int E = in_sizes[7] / 2;    // 800000
    const int EP = E + 3 * N + 16;    // padded edge-slot capacity

    float*    q       = (float*)d_ws;
    float*    k       = q + (size_t)N * H;
    float*    v       = k + (size_t)N * H;
    float*    exps    = v + (size_t)N * H;
    unsigned* epack   = (unsigned*)(exps + EP);
    int*      counts  = (int*)(epack + EP);
    int*      offsets = counts + N;
    int*      cursor  = offsets + N;
    int*      bsum    = cursor + N;
    float*    denom8  = (float*)(bsum + 64);
    int*      counts8 = (int*)(denom8 + 8 * NSEG);   // 8N ints

    hipMemsetAsync(denom8, 0, 8 * NSEG * sizeof(float), stream);

    const int NT    = (N + MB - 1) / MB;     // 782 row tiles
    const int NC2   = (E + 2047) / 2048;     // 391 reorder chunks
    const int nspan = (N + 7) / 8;           // dst-range span per class
    const int NBSC  = (N + SCB - 1) / SCB;   // 25 scan blocks

    hist8_kernel<<<64, 1024, 0, stream>>>(ei, counts8, N, E, nspan);

    qkv_mfma<<<256, 768, 0, stream>>>(
        x, Wq, Wk, Wv, bq, bk, bv, q, k, v, N, NT);

    scanA<<<NBSC, 256, 0, stream>>>(counts8, counts, offsets, bsum, N);
    scanB<<<1, 64, 0, stream>>>(bsum, NBSC);
    scanC<<<NBSC, 256, 0, stream>>>(bsum, offsets, cursor, N);

    reorder_kernel<<<8 * NC2, 256, 0, stream>>>(
        ei, batch, cursor, epack, E, N, nspan);

    score_kernel<<<2048, 256, 0, stream>>>(
        q, k, epack, offsets, counts, exps, denom8, N);

    accum_kernel<<<(N + 3) / 4, 256, 0, stream>>>(
        v, exps, epack, offsets, counts, denom8, (float*)d_out, N);
}